// Round 6
// baseline (990.227 us; speedup 1.0000x reference)
//
#include <hip/hip_runtime.h>
#include <hip/hip_fp16.h>
#include <math.h>

#ifndef M_PI
#define M_PI 3.14159265358979323846
#endif

// Problem constants
#define BB 2
#define VV 180
#define RR 32
#define CC 512
#define NPIX 512

#define PADL 106     // left padding of t-range
#define PW 724       // padded width: t_real in [-106, 617]
#define TCEN 362     // index recentering offset

// pair-orbit backprojection tiling
#define SH3 8        // rep-rows per block
#define CHP 2        // angle-PAIRS per LDS chunk
#define NCHP 45      // 45 * 2 = 90 pairs = 180 angles

// fallback tiling (round-3 kernels)
#define SH 16
#define CH2 6
#define NCHUNK2 30

// ws layout (floats):
//   [0,1024)      h_ext (impulse response, duplicated, scaled by pi/V)
//   [1024,1384)   legacy trig: cos[180] | sin[180]          (fallback path)
//   [1408,1768)   trig2: interleaved (cos,sin) float2[180]  (pair path uses first 90)
//   [2048,...)    pair path: fp16 table [64 slices][90 pairs][724] x 4 halves = 33.4 MB
//                 fallback:  filt [b][r][v][c] = 23.6 MB
#define TAB_OFF 2048
#define FILT_OFF 2048

// ---------------------------------------------------------------------------
// Kernel A: ramp-filter impulse response h[k] (scaled by pi/V) + angle tables.
// ---------------------------------------------------------------------------
__global__ void precompute_kernel(float* __restrict__ ws) {
    int j = blockIdx.x * blockDim.x + threadIdx.x;  // 0..511
    if (j < 512) {
        float s = 0.f;
        for (int m = 1; m < 512; ++m) {             // m=0 term has ramp=0
            int p = (m * j) & 511;                  // exact (m*j) mod 512
            float ang = (float)(2.0 * M_PI / 512.0) * (float)p;
            int mm = m < 512 - m ? m : 512 - m;
            float ramp = 2.0f * (float)mm * (1.0f / 512.0f);
            s += ramp * cosf(ang);
        }
        s *= (1.0f / 512.0f);
        s *= (float)(M_PI / (double)VV);            // fold backprojection scale
        ws[j] = s;
        ws[j + 512] = s;                            // h_ext[j+512] == h[j]
    }
    if (j < VV) {
        float th = (float)((double)j * M_PI / 180.0);
        float c = cosf(th), sn = sinf(th);
        ws[1024 + j] = c;
        ws[1024 + 180 + j] = sn;
        ws[1408 + 2 * j] = c;
        ws[1408 + 2 * j + 1] = sn;
    }
}

// ---------------------------------------------------------------------------
// Kernel B (pair path): ramp-filter convolution; epilogue writes the padded
// fp16 coefficient table in PAIRED layout. Cell = 8 bytes:
//   [half2 (f0_v, d_v)] [half2 (f0_{v+90}, d_{v+90})]
// value(u) = f0 + w*d with w = u - floor(u); pads have d=0 (edge clamp).
// Each conv block handles one angle v and writes one 4-byte half of each cell.
// ---------------------------------------------------------------------------
__global__ __launch_bounds__(128) void conv_table_kernel(const float* __restrict__ sino,
                                                         const float* __restrict__ ws,
                                                         unsigned int* __restrict__ table) {
    __shared__ float rows_s[16 * 512];  // 32 KiB
    __shared__ float h_s[1024];         // 4 KiB
    int t = threadIdx.x;
    int blk = blockIdx.x;               // 0..719
    int bv = blk >> 1;                  // b*180 + v
    int half = blk & 1;                 // which 16 of the 32 r's
    int b = bv / 180;
    int v = bv - b * 180;

    const float4* src4 = (const float4*)(sino + (((size_t)bv * 32) + (size_t)half * 16) * 512);
    float4* rows4 = (float4*)rows_s;
    for (int i = t; i < 2048; i += 128) rows4[i] = src4[i];
    for (int i = t; i < 1024; i += 128) h_s[i] = ws[i];
    __syncthreads();

    int wave = t >> 6;
    int lane = t & 63;
    int row0 = wave * 8;

    float acc[8][8];
#pragma unroll
    for (int j = 0; j < 8; ++j)
#pragma unroll
        for (int i = 0; i < 8; ++i) acc[j][i] = 0.f;

    for (int k = 0; k < 512; k += 4) {
        float4 rv[8];
#pragma unroll
        for (int j = 0; j < 8; ++j)
            rv[j] = *(const float4*)&rows_s[(row0 + j) * 512 + k];
#pragma unroll
        for (int u = 0; u < 4; ++u) {
            float hv[8];
            int base = lane - (k + u) + 512;   // in [1, 1023]
#pragma unroll
            for (int i = 0; i < 8; ++i) hv[i] = h_s[base + 64 * i];
#pragma unroll
            for (int j = 0; j < 8; ++j) {
                float rj = (u == 0) ? rv[j].x : (u == 1) ? rv[j].y : (u == 2) ? rv[j].z : rv[j].w;
#pragma unroll
                for (int i = 0; i < 8; ++i) acc[j][i] = fmaf(rj, hv[i], acc[j][i]);
            }
        }
    }

    // Epilogue: round-trip filtered rows through LDS, emit fp16 (f0,d) halves.
    __syncthreads();
#pragma unroll
    for (int j = 0; j < 8; ++j)
#pragma unroll
        for (int i = 0; i < 8; ++i)
            rows_s[(row0 + j) * 512 + lane + 64 * i] = acc[j][i];
    __syncthreads();

    int p = (v < 90) ? v : v - 90;
    int halfSel = (v < 90) ? 0 : 1;     // which u32 of the 8-byte cell
    for (int jj = 0; jj < 16; ++jj) {
        const float* fr = rows_s + jj * 512;
        int slice = b * 32 + half * 16 + jj;
        unsigned int* trow = table + (((size_t)slice * 90 + p) * PW) * 2 + halfSel;
        for (int cx = t; cx < PW; cx += 128) {
            int s0 = cx - PADL;
            int i0 = min(max(s0, 0), 511);
            int i1 = min(max(s0 + 1, 0), 511);
            float f0 = fr[i0];
            float d = fr[i1] - f0;
            __half2 h = __floats2half2_rn(f0, d);   // lo=f0, hi=d
            trow[(size_t)cx * 2] = *(unsigned int*)&h;
        }
    }
}

// ---------------------------------------------------------------------------
// Kernel C (pair path): orbit backprojection with fp16 table. One lane = one
// 4-pixel rotation orbit. Each ds_read_b64 of (f0_v,d_v,f0_w,d_w) serves TWO
// samples. 12 KB LDS chunk -> all 8 blocks/CU resident.
// Accumulate via v_fma_mix (f16 operand, f32 acc).
// ---------------------------------------------------------------------------
__global__ __launch_bounds__(256, 8) void backproj_pairh_kernel(const uint2* __restrict__ tab,
                                                                const float2* __restrict__ trigp,
                                                                float* __restrict__ out) {
    __shared__ __align__(16) uint2 pbuf[CHP * PW];   // 11584 B
    __shared__ float2 trig_s[90];
    int t = threadIdx.x;
    int slice = blockIdx.y;             // b*32 + r
    int strip = blockIdx.x;             // 0..31
    int y0 = strip * SH3;               // rep-row offset in [0,256)
    const uint2* tslice = tab + (size_t)slice * (90 * PW);

    for (int i = t; i < 90; i += 256) trig_s[i] = trigp[i];

    float xc = (float)t + 0.5f;         // rep px = 256+t  ->  xc = px-255.5

    float acc0[SH3], acc1[SH3], acc2[SH3], acc3[SH3];
#pragma unroll
    for (int j = 0; j < SH3; ++j) { acc0[j] = 0.f; acc1[j] = 0.f; acc2[j] = 0.f; acc3[j] = 0.f; }

    for (int chunk = 0; chunk < NCHP; ++chunk) {
        __syncthreads();                // previous chunk consumed (covers trig_s on chunk 0)
        const float4* src = (const float4*)(tslice + chunk * (CHP * PW));
        float4* dst = (float4*)pbuf;
        for (int i = t; i < (CHP * PW) / 2; i += 256) dst[i] = src[i];
        __syncthreads();
#pragma unroll
        for (int pa = 0; pa < CHP; ++pa) {
            float2 cs = trig_s[chunk * CHP + pa];
            const uint2* pb = pbuf + pa * PW + TCEN;
#pragma unroll
            for (int j = 0; j < SH3; ++j) {
                float ycj = (float)(y0 + j) + 0.5f;
                float ua = fmaf(xc, cs.x, fmaf(ycj, cs.y, -0.5f));   // x c + y s - .5
                float ub = fmaf(xc, cs.y, fmaf(-ycj, cs.x, -0.5f));  // x s - y c - .5
                float uma = -1.0f - ua;
                float umb = -1.0f - ub;

                float fa = floorf(ua);  int ma  = (int)fa;  float wa  = ua  - fa;
                float fm = floorf(uma); int mma = (int)fm;  float wma = uma - fm;
                float fb = floorf(ub);  int mb  = (int)fb;  float wb  = ub  - fb;
                float fn = floorf(umb); int mmb = (int)fn;  float wmb = umb - fn;

                uint2 qa  = pb[ma];
                uint2 qma = pb[mma];
                uint2 qb  = pb[mb];
                uint2 qmb = pb[mmb];
                __half2 qa0  = *(const __half2*)&qa.x,  qa1  = *(const __half2*)&qa.y;
                __half2 qma0 = *(const __half2*)&qma.x, qma1 = *(const __half2*)&qma.y;
                __half2 qb0  = *(const __half2*)&qb.x,  qb1  = *(const __half2*)&qb.y;
                __half2 qmb0 = *(const __half2*)&qmb.x, qmb1 = *(const __half2*)&qmb.y;

                acc0[j] = fmaf(wa,  __high2float(qa0),  acc0[j]) + __low2float(qa0);   // P0 @ v
                acc1[j] = fmaf(wa,  __high2float(qa1),  acc1[j]) + __low2float(qa1);   // P1 @ v+90
                acc2[j] = fmaf(wma, __high2float(qma0), acc2[j]) + __low2float(qma0);  // P2 @ v
                acc3[j] = fmaf(wma, __high2float(qma1), acc3[j]) + __low2float(qma1);  // P3 @ v+90
                acc1[j] = fmaf(wb,  __high2float(qb0),  acc1[j]) + __low2float(qb0);   // P1 @ v
                acc2[j] = fmaf(wb,  __high2float(qb1),  acc2[j]) + __low2float(qb1);   // P2 @ v+90
                acc3[j] = fmaf(wmb, __high2float(qmb0), acc3[j]) + __low2float(qmb0);  // P3 @ v
                acc0[j] = fmaf(wmb, __high2float(qmb1), acc0[j]) + __low2float(qmb1);  // P0 @ v+90
            }
        }
    }

    // Orbit writes. P0/P2 row-coalesced; P1/P3 column-orbit (accepted).
    int px = 256 + t;
    size_t sbase = (size_t)slice * (512 * 512);
#pragma unroll
    for (int j = 0; j < SH3; ++j) {
        int py = 256 + y0 + j;
        float v0 = acc0[j], v1 = acc1[j], v2 = acc2[j], v3 = acc3[j];
        out[sbase + (size_t)py * 512 + px]                 = v0 > 0.f ? v0 : 0.f;  // (px, py)
        out[sbase + (size_t)px * 512 + (511 - py)]         = v1 > 0.f ? v1 : 0.f;  // (511-py, px)
        out[sbase + (size_t)(511 - py) * 512 + (511 - px)] = v2 > 0.f ? v2 : 0.f;  // (511-px, 511-py)
        out[sbase + (size_t)(511 - px) * 512 + py]         = v3 > 0.f ? v3 : 0.f;  // (py, 511-px)
    }
}

// ===========================================================================
// Fallback path (round-3 kernels) - used only if ws_size can't hold the table.
// ===========================================================================
__global__ __launch_bounds__(128) void conv_kernel(const float* __restrict__ sino,
                                                   const float* __restrict__ ws,
                                                   float* __restrict__ filt) {
    __shared__ float rows_s[16 * 512];
    __shared__ float h_s[1024];
    int t = threadIdx.x;
    int blk = blockIdx.x;
    int bv = blk >> 1;
    int half = blk & 1;
    int b = bv / 180;
    int v = bv - b * 180;

    const float4* src4 = (const float4*)(sino + (((size_t)bv * 32) + (size_t)half * 16) * 512);
    float4* rows4 = (float4*)rows_s;
    for (int i = t; i < 2048; i += 128) rows4[i] = src4[i];
    for (int i = t; i < 1024; i += 128) h_s[i] = ws[i];
    __syncthreads();

    int wave = t >> 6;
    int lane = t & 63;
    int row0 = wave * 8;

    float acc[8][8];
#pragma unroll
    for (int j = 0; j < 8; ++j)
#pragma unroll
        for (int i = 0; i < 8; ++i) acc[j][i] = 0.f;

    for (int k = 0; k < 512; k += 4) {
        float4 rv[8];
#pragma unroll
        for (int j = 0; j < 8; ++j)
            rv[j] = *(const float4*)&rows_s[(row0 + j) * 512 + k];
#pragma unroll
        for (int u = 0; u < 4; ++u) {
            float hv[8];
            int base = lane - (k + u) + 512;
#pragma unroll
            for (int i = 0; i < 8; ++i) hv[i] = h_s[base + 64 * i];
#pragma unroll
            for (int j = 0; j < 8; ++j) {
                float rj = (u == 0) ? rv[j].x : (u == 1) ? rv[j].y : (u == 2) ? rv[j].z : rv[j].w;
#pragma unroll
                for (int i = 0; i < 8; ++i) acc[j][i] = fmaf(rj, hv[i], acc[j][i]);
            }
        }
    }

#pragma unroll
    for (int j = 0; j < 8; ++j) {
        int r = half * 16 + row0 + j;
        float* dst = filt + (((size_t)b * 32 + r) * 180 + v) * 512;
#pragma unroll
        for (int i = 0; i < 8; ++i) dst[lane + 64 * i] = acc[j][i];
    }
}

__global__ __launch_bounds__(256) void backproj_kernel(const float* __restrict__ filt,
                                                       const float* __restrict__ trig,
                                                       float* __restrict__ out) {
    __shared__ float2 pbuf[CH2][PW];
    __shared__ float trig_s[360];
    int t = threadIdx.x;
    int slice = blockIdx.y;
    int strip = blockIdx.x;
    int y0 = strip * SH;
    int lane = t & 63;
    int wave = t >> 6;
    int x0 = wave * 128;
    const float* slice_p = filt + (size_t)slice * (180 * 512);

    for (int i = t; i < 360; i += 256) trig_s[i] = trig[i];

    float xc0 = (float)(x0 + lane) - 255.5f;
    float xc1 = xc0 + 64.0f;
    float yb0 = (float)y0 - 255.5f;

    float acc[2][SH];
#pragma unroll
    for (int g = 0; g < 2; ++g)
#pragma unroll
        for (int j = 0; j < SH; ++j) acc[g][j] = 0.f;

    for (int chunk = 0; chunk < NCHUNK2; ++chunk) {
        int v0 = chunk * CH2;
        __syncthreads();
#pragma unroll 1
        for (int a = 0; a < CH2; ++a) {
            const float* prow = slice_p + (v0 + a) * 512;
            for (int cx = t; cx < PW; cx += 256) {
                int s0 = cx - PADL;
                int i0 = min(max(s0, 0), 511);
                int i1 = min(max(s0 + 1, 0), 511);
                float f0 = prow[i0];
                float d = prow[i1] - f0;
                float m = (float)(cx - TCEN);
                pbuf[a][cx] = make_float2(fmaf(-m, d, f0), d);
            }
        }
        __syncthreads();
#pragma unroll 1
        for (int a = 0; a < CH2; ++a) {
            float cth = trig_s[v0 + a];
            float sth = trig_s[180 + v0 + a];
            float ybase = fmaf(yb0, sth, 255.5f + (float)PADL - (float)TCEN);
            float t0 = fmaf(xc0, cth, ybase);
            float t1 = fmaf(xc1, cth, ybase);
            const char* pb = (const char*)pbuf;
            int aoff = a * (PW * 8) + TCEN * 8;
#pragma unroll
            for (int j = 0; j < SH; ++j) {
                int m0 = (int)floorf(t0);
                float2 g0 = *(const float2*)(pb + (m0 * 8 + aoff));
                acc[0][j] = fmaf(t0, g0.y, acc[0][j]) + g0.x;
                t0 += sth;

                int m1 = (int)floorf(t1);
                float2 g1 = *(const float2*)(pb + (m1 * 8 + aoff));
                acc[1][j] = fmaf(t1, g1.y, acc[1][j]) + g1.x;
                t1 += sth;
            }
        }
    }

    size_t obase = ((size_t)slice * 512 + (size_t)y0) * 512;
#pragma unroll
    for (int j = 0; j < SH; ++j) {
        float v0o = acc[0][j];
        float v1o = acc[1][j];
        out[obase + (size_t)j * 512 + x0 + lane] = v0o > 0.f ? v0o : 0.f;
        out[obase + (size_t)j * 512 + x0 + 64 + lane] = v1o > 0.f ? v1o : 0.f;
    }
}

extern "C" void kernel_launch(void* const* d_in, const int* in_sizes, int n_in,
                              void* d_out, int out_size, void* d_ws, size_t ws_size,
                              hipStream_t stream) {
    const float* sino = (const float*)d_in[0];
    float* out = (float*)d_out;
    float* ws = (float*)d_ws;

    size_t tableWords = (size_t)64 * 90 * PW * 2;              // u32 words (fp16 table)
    size_t needed = TAB_OFF * sizeof(float) + tableWords * 4;  // ~33.4 MB

    precompute_kernel<<<2, 256, 0, stream>>>(ws);
    if (ws_size >= needed) {
        unsigned int* table = (unsigned int*)(ws + TAB_OFF);
        conv_table_kernel<<<720, 128, 0, stream>>>(sino, ws, table);
        backproj_pairh_kernel<<<dim3(32, 64), 256, 0, stream>>>((const uint2*)table,
                                                                (const float2*)(ws + 1408), out);
    } else {
        float* filt = ws + FILT_OFF;
        conv_kernel<<<720, 128, 0, stream>>>(sino, ws, filt);
        backproj_kernel<<<dim3(32, 64), 256, 0, stream>>>(filt, ws + 1024, out);
    }
}